// Round 1
// baseline (232.876 us; speedup 1.0000x reference)
//
#include <hip/hip_runtime.h>

// LIF neuron over [T, B, C, H, W] = [8, 32, 128, 32, 32] fp32.
// V_new = V + (-V/TAU + x_t); spike = (V_new>=1) - (V_new<=-1); hard reset.
// One thread owns 4 spatial elements (float4) across all T steps; V stays in
// registers. Memory-bound: 256 MiB total traffic, ~41 us roofline @ 6.3 TB/s.

#define T_STEPS 8

__device__ __forceinline__ float lif_step(float& V, float x) {
    const float TAU = (float)(5.0 / 3.0);  // fp32 1.66666663, matches np cast
    // Replicate reference op order exactly: neg, divide (IEEE), add, add.
    float dv = (-V) / TAU + x;
    float Vn = V + dv;
    float o = (Vn >= 1.0f ? 1.0f : 0.0f) - (Vn <= -1.0f ? 1.0f : 0.0f);
    V = (o == 0.0f) ? Vn : 0.0f;  // o is exactly -1/0/+1
    return o;
}

__global__ __launch_bounds__(256) void lif_kernel(const float4* __restrict__ x,
                                                  float4* __restrict__ out,
                                                  int n4) {
    int i = blockIdx.x * blockDim.x + threadIdx.x;
    if (i >= n4) return;

    float4 V = make_float4(0.f, 0.f, 0.f, 0.f);
#pragma unroll
    for (int t = 0; t < T_STEPS; ++t) {
        size_t idx = (size_t)t * n4 + i;
        float4 xt = x[idx];
        float4 o;
        o.x = lif_step(V.x, xt.x);
        o.y = lif_step(V.y, xt.y);
        o.z = lif_step(V.z, xt.z);
        o.w = lif_step(V.w, xt.w);
        out[idx] = o;
    }
}

extern "C" void kernel_launch(void* const* d_in, const int* in_sizes, int n_in,
                              void* d_out, int out_size, void* d_ws, size_t ws_size,
                              hipStream_t stream) {
    const float* x = (const float*)d_in[0];
    float* out = (float*)d_out;

    int total = in_sizes[0];            // T*B*C*H*W = 33554432
    int n = total / T_STEPS;            // spatial elements per timestep
    int n4 = n / 4;                     // float4 groups (n divisible by 4)

    dim3 block(256);
    dim3 grid((n4 + block.x - 1) / block.x);
    lif_kernel<<<grid, block, 0, stream>>>((const float4*)x, (float4*)out, n4);
}